// Round 3
// baseline (1340.683 us; speedup 1.0000x reference)
//
#include <hip/hip_runtime.h>
#include <hip/hip_bf16.h>
#include <math.h>

#define NB    4
#define NTOK  8192
#define DIM   1024
#define HDIM  512
#define NKEEP 4096

// ---------------------------------------------------------------------------
// Kernel A: fused scorer  scores[g] = W2 . gelu(tokens[g] @ W1 + b1) + b2
// 256 blocks (128 tokens each, 1/CU), 512 threads (8 waves), 2 waves/SIMD.
// Wave w owns tokens t0=w*16..+15. A-operand is wave-uniform -> loaded straight
// from global as broadcast float4 (no LDS), software-pipelined 1 group ahead
// in a statically-indexed 2-deep register buffer. Only B (W1) is LDS-staged
// via global_load_lds, double-buffered. Lane owns j = {lane*4..+3, 256+...}:
// B ds_read_b128 fully conflict-free. fp32 VALU FMA (no fp32 MFMA on CDNA4;
// bf16-split GEMM too imprecise for exact top-k index agreement).
// ---------------------------------------------------------------------------
#define TM  128
#define KC  16
#define NCHUNK (DIM / KC)
#define TPW 16

#define GLD16(g, s) __builtin_amdgcn_global_load_lds(                       \
    (const __attribute__((address_space(1))) void*)(g),                    \
    (__attribute__((address_space(3))) void*)(s), 16, 0, 0)

__global__ __launch_bounds__(512)
__attribute__((amdgpu_waves_per_eu(2, 2)))
void dtr_scores_kernel(const float* __restrict__ tokens,
                       const float* __restrict__ W1,
                       const float* __restrict__ b1g,
                       const float* __restrict__ W2,
                       const float* __restrict__ b2g,
                       float* __restrict__ scores)
{
    __shared__ __align__(16) float Bs[2][KC][HDIM];  // 32 KB per buf

    const int tid   = threadIdx.x;
    const int wid   = tid >> 6;
    const int lane  = tid & 63;
    const int gtok0 = blockIdx.x * TM;
    const int t0    = wid * TPW;
    const int j0    = lane * 4;

    const float* arow = tokens + (size_t)(gtok0 + t0) * DIM;  // wave-uniform

    float acc[TPW][8];
#pragma unroll
    for (int i = 0; i < TPW; ++i)
#pragma unroll
        for (int jj = 0; jj < 8; ++jj) acc[i][jj] = 0.0f;

    // B tile staging: rows c*16..+15 of W1 = 32 KB contiguous; 4 x 16B/thread
    auto stageB = [&](int buf, int c) {
        const float* gb = W1 + (size_t)c * KC * HDIM;
        float* sb = &Bs[buf][0][0];
#pragma unroll
        for (int p = 0; p < 4; ++p) {
            const int f = tid * 4 + p * 2048;
            GLD16(gb + f, sb + f);
        }
    };

    // A group load: 8 token rows (h-half), 4 consecutive k -> 8 broadcast f4
    auto loadA = [&](float4* dst, int kcol, int h) {
#pragma unroll
        for (int i = 0; i < 8; ++i)
            dst[i] = *reinterpret_cast<const float4*>(
                arow + (size_t)(h * 8 + i) * DIM + kcol);
    };

    float4 abuf[2][8];           // 2-deep pipeline, statically indexed
    stageB(0, 0);
    loadA(abuf[0], 0, 0);        // group g=0 of chunk 0
    __syncthreads();

    int buf = 0;
    for (int c = 0; c < NCHUNK; ++c) {
        const int kb  = c * KC;
        const int kbn = (c + 1 < NCHUNK) ? (c + 1) * KC : c * KC;
        if (c + 1 < NCHUNK) stageB(buf ^ 1, c + 1);

#pragma unroll
        for (int kq = 0; kq < 4; ++kq) {
            // B fragments for 4 consecutive k (lane*16B: conflict-free)
            float4 bl[4], bh[4];
#pragma unroll
            for (int q = 0; q < 4; ++q) {
                bl[q] = *reinterpret_cast<const float4*>(&Bs[buf][kq * 4 + q][j0]);
                bh[q] = *reinterpret_cast<const float4*>(&Bs[buf][kq * 4 + q][256 + j0]);
            }
#pragma unroll
            for (int h = 0; h < 2; ++h) {
                const int g = kq * 2 + h;            // 0..7, compile-time
                const float4* aC = abuf[g & 1];
                float4*       aN = abuf[(g + 1) & 1];
                // prefetch next group (next chunk's g=0 when g==7)
                if (g < 7) loadA(aN, kb + ((g + 1) >> 1) * 4, (g + 1) & 1);
                else       loadA(aN, kbn, 0);
#pragma unroll
                for (int i = 0; i < 8; ++i) {
                    const float av[4] = {aC[i].x, aC[i].y, aC[i].z, aC[i].w};
                    float* A8 = acc[h * 8 + i];
#pragma unroll
                    for (int q = 0; q < 4; ++q) {
                        A8[0] = fmaf(av[q], bl[q].x, A8[0]);
                        A8[1] = fmaf(av[q], bl[q].y, A8[1]);
                        A8[2] = fmaf(av[q], bl[q].z, A8[2]);
                        A8[3] = fmaf(av[q], bl[q].w, A8[3]);
                        A8[4] = fmaf(av[q], bh[q].x, A8[4]);
                        A8[5] = fmaf(av[q], bh[q].y, A8[5]);
                        A8[6] = fmaf(av[q], bh[q].z, A8[6]);
                        A8[7] = fmaf(av[q], bh[q].w, A8[7]);
                    }
                }
            }
        }
        __syncthreads();
        buf ^= 1;
    }

    // --- epilogue: exact GELU + W2 dot, 64-lane butterfly reduce per token ---
    const float4 w2a = *reinterpret_cast<const float4*>(&W2[j0]);
    const float4 w2b = *reinterpret_cast<const float4*>(&W2[256 + j0]);
    const float4 b1a = *reinterpret_cast<const float4*>(&b1g[j0]);
    const float4 b1b = *reinterpret_cast<const float4*>(&b1g[256 + j0]);
    const float ww[8] = {w2a.x, w2a.y, w2a.z, w2a.w, w2b.x, w2b.y, w2b.z, w2b.w};
    const float bb[8] = {b1a.x, b1a.y, b1a.z, b1a.w, b1b.x, b1b.y, b1b.z, b1b.w};

    const float bias2 = b2g[0];
#pragma unroll
    for (int i = 0; i < TPW; ++i) {
        float s = 0.0f;
#pragma unroll
        for (int jj = 0; jj < 8; ++jj) {
            const float h = acc[i][jj] + bb[jj];
            const float g = 0.5f * h * (1.0f + erff(h * 0.70710678118654752f));
            s = fmaf(g, ww[jj], s);
        }
#pragma unroll
        for (int off = 32; off > 0; off >>= 1)
            s += __shfl_xor(s, off, 64);
        if (lane == 0) scores[gtok0 + t0 + i] = s + bias2;
    }
}

// ---------------------------------------------------------------------------
// Block-wide exclusive scan (1024 threads, one int per thread). lds >= 16 ints.
// ---------------------------------------------------------------------------
__device__ __forceinline__ int blk_excl_scan_1024(int v, int tid, int* lds, int* tot)
{
    const int lane = tid & 63;
    const int wid  = tid >> 6;
    int x = v;
#pragma unroll
    for (int d = 1; d < 64; d <<= 1) {
        const int y = __shfl_up(x, d, 64);
        if (lane >= d) x += y;
    }
    if (lane == 63) lds[wid] = x;          // inclusive wave sums
    __syncthreads();
    if (wid == 0) {
        int w = (lane < 16) ? lds[lane] : 0;
#pragma unroll
        for (int d = 1; d < 16; d <<= 1) {
            const int y = __shfl_up(w, d, 64);
            if (lane >= d) w += y;
        }
        if (lane < 16) lds[lane] = w;      // inclusive scanned wave sums
    }
    __syncthreads();
    const int wave_off = (wid == 0) ? 0 : lds[wid - 1];
    const int total    = lds[15];
    __syncthreads();                       // lds reusable after return
    *tot = total;
    return wave_off + x - v;               // exclusive prefix
}

// ---------------------------------------------------------------------------
// Kernel B: exact top-k per batch. Bitonic-sort a copy of scores in LDS to get
// the threshold (4096th largest), tie-break by lowest index (matches
// jax.lax.top_k + sort(indices)), emit sorted compacted indices + 0/1 mask.
// ---------------------------------------------------------------------------
__global__ __launch_bounds__(1024)
void dtr_topk_kernel(const float* __restrict__ scores,
                     int* __restrict__ idx_out,
                     float* __restrict__ mask_out)
{
    __shared__ float sv[NTOK];   // 32 KB
    __shared__ int scan_lds[16];

    const int b   = blockIdx.x;
    const int tid = threadIdx.x;
    const float* s = scores + (size_t)b * NTOK;

    for (int i = tid; i < NTOK; i += 1024) sv[i] = s[i];
    __syncthreads();

    // bitonic sort ascending
    for (int k = 2; k <= NTOK; k <<= 1) {
        for (int j = k >> 1; j > 0; j >>= 1) {
            for (int i = tid; i < NTOK; i += 1024) {
                const int ixj = i ^ j;
                if (ixj > i) {
                    const float av = sv[i];
                    const float bv = sv[ixj];
                    const bool asc = ((i & k) == 0);
                    if ((av > bv) == asc) { sv[i] = bv; sv[ixj] = av; }
                }
            }
            __syncthreads();
        }
    }

    const float T = sv[NTOK - NKEEP];   // 4096th largest (ascending pos 4096)

    const int i0 = tid * 8;
    float sc[8];
#pragma unroll
    for (int q = 0; q < 8; ++q) sc[q] = s[i0 + q];

    int sum_g = 0, sum_e = 0;
#pragma unroll
    for (int q = 0; q < 8; ++q) {
        sum_g += (sc[q] > T) ? 1 : 0;
        sum_e += (sc[q] == T) ? 1 : 0;
    }
    int tot_g, tot_e;
    (void)blk_excl_scan_1024(sum_g, tid, scan_lds, &tot_g);
    const int off_e = blk_excl_scan_1024(sum_e, tid, scan_lds, &tot_e);

    const int need = NKEEP - tot_g;     // how many ==T to keep (lowest index first)

    int keep[8];
    int sum_k = 0;
    int er = off_e;
#pragma unroll
    for (int q = 0; q < 8; ++q) {
        int kf = 0;
        if (sc[q] > T) kf = 1;
        else if (sc[q] == T) { kf = (er < need) ? 1 : 0; ++er; }
        keep[q] = kf;
        sum_k += kf;
    }
    int tot_k;
    int pos = blk_excl_scan_1024(sum_k, tid, scan_lds, &tot_k);

#pragma unroll
    for (int q = 0; q < 8; ++q) {
        mask_out[(size_t)b * NTOK + i0 + q] = keep[q] ? 1.0f : 0.0f;
        if (keep[q]) {
            idx_out[(size_t)b * NKEEP + pos] = i0 + q;
            ++pos;
        }
    }
}

// ---------------------------------------------------------------------------
// Kernel C: gather selected token rows. One block per (b, kpos): 1024 floats.
// ---------------------------------------------------------------------------
__global__ __launch_bounds__(256)
void dtr_gather_kernel(const float* __restrict__ tokens,
                       const int* __restrict__ idx,
                       float* __restrict__ selected)
{
    const int g    = blockIdx.x;        // 0 .. NB*NKEEP-1
    const int b    = g >> 12;           // / NKEEP
    const int src  = idx[g];
    const float4* sp = reinterpret_cast<const float4*>(
        tokens + ((size_t)b * NTOK + (size_t)src) * DIM);
    float4* dp = reinterpret_cast<float4*>(selected + (size_t)g * DIM);
    dp[threadIdx.x] = sp[threadIdx.x];
}

// ---------------------------------------------------------------------------
extern "C" void kernel_launch(void* const* d_in, const int* in_sizes, int n_in,
                              void* d_out, int out_size, void* d_ws, size_t ws_size,
                              hipStream_t stream)
{
    const float* tokens = (const float*)d_in[0];  // [4,8192,1024]
    const float* W1     = (const float*)d_in[1];  // [1024,512]
    const float* b1     = (const float*)d_in[2];  // [512]
    const float* W2     = (const float*)d_in[3];  // [512,1]
    const float* b2     = (const float*)d_in[4];  // [1]

    float* out      = (float*)d_out;
    float* selected = out;                                   // 4*4096*1024
    float* mask     = out + (size_t)NB * NKEEP * DIM;        // 4*8192

    float* scores = (float*)d_ws;                            // 32768 f32
    int*   idx    = (int*)((char*)d_ws + (size_t)NB * NTOK * sizeof(float));

    dtr_scores_kernel<<<(NB * NTOK) / TM, 512, 0, stream>>>(
        tokens, W1, b1, W2, b2, scores);
    dtr_topk_kernel<<<NB, 1024, 0, stream>>>(scores, idx, mask);
    dtr_gather_kernel<<<NB * NKEEP, 256, 0, stream>>>(tokens, idx, selected);
}

// Round 4
// 740.054 us; speedup vs baseline: 1.8116x; 1.8116x over previous
//
#include <hip/hip_runtime.h>
#include <hip/hip_bf16.h>
#include <math.h>

#define NB    4
#define NTOK  8192
#define DIM   1024
#define HDIM  512
#define NKEEP 4096

// ---------------------------------------------------------------------------
// Kernel A: fused scorer  scores[g] = W2 . gelu(tokens[g] @ W1 + b1) + b2
// 512 blocks (64 tokens, 2 blocks/CU), 512 threads (8 waves).
// Wave w owns tokens t0=w*8..+7; lane owns j = {lane*4..+3, 256+lane*4..+3}.
// A-operand is wave-uniform -> broadcast float4 loads straight from global
// (one 64B line per row per chunk, L1-resident; NO deep reg pipeline -> no
// spill). B (W1) LDS-staged via global_load_lds, double-buffered; ds_read_b128
// at lane*16B: conflict-free. acc[8][8]=64 regs; peak live ~110 VGPR, capped
// at 128 via __launch_bounds__(512,4) so 2 blocks/CU co-reside and hide the
// per-chunk barrier drains. fp32 VALU FMA (no fp32 MFMA on CDNA4; bf16-split
// too imprecise for exact top-k index agreement).
// ---------------------------------------------------------------------------
#define TM  64
#define KC  16
#define NCHUNK (DIM / KC)
#define TPW 8

#define GLD16(g, s) __builtin_amdgcn_global_load_lds(                       \
    (const __attribute__((address_space(1))) void*)(g),                    \
    (__attribute__((address_space(3))) void*)(s), 16, 0, 0)

__global__ __launch_bounds__(512, 4)
void dtr_scores_kernel(const float* __restrict__ tokens,
                       const float* __restrict__ W1,
                       const float* __restrict__ b1g,
                       const float* __restrict__ W2,
                       const float* __restrict__ b2g,
                       float* __restrict__ scores)
{
    __shared__ __align__(16) float Bs[2][KC][HDIM];  // 32 KB per buf

    const int tid   = threadIdx.x;
    const int wid   = __builtin_amdgcn_readfirstlane(tid >> 6);
    const int lane  = tid & 63;
    const int gtok0 = blockIdx.x * TM;
    const int t0    = wid * TPW;
    const int j0    = lane * 4;

    const float* arow = tokens + (size_t)(gtok0 + t0) * DIM;  // wave-uniform

    float acc[TPW][8];
#pragma unroll
    for (int i = 0; i < TPW; ++i)
#pragma unroll
        for (int jj = 0; jj < 8; ++jj) acc[i][jj] = 0.0f;

    // B tile staging: rows c*16..+15 of W1 = 32 KB contiguous; 4 x 16B/thread
    auto stageB = [&](int buf, int c) {
        const float* gb = W1 + (size_t)c * KC * HDIM;
        float* sb = &Bs[buf][0][0];
#pragma unroll
        for (int p = 0; p < 4; ++p) {
            const int f = tid * 4 + p * 2048;
            GLD16(gb + f, sb + f);
        }
    };

    stageB(0, 0);
    __syncthreads();

    int buf = 0;
    for (int c = 0; c < NCHUNK; ++c) {
        if (c + 1 < NCHUNK) stageB(buf ^ 1, c + 1);
        const int kb = c * KC;

#pragma unroll
        for (int kq = 0; kq < 4; ++kq) {
            // A: 8 token rows x 4 consecutive k, broadcast (wave-uniform addr)
            float4 a[TPW];
#pragma unroll
            for (int i = 0; i < TPW; ++i)
                a[i] = *reinterpret_cast<const float4*>(
                    arow + (size_t)i * DIM + kb + kq * 4);

#pragma unroll
            for (int q = 0; q < 4; ++q) {
                // B row k = kb+kq*4+q, lane's 2 j-quads (16B reads, no conflict)
                const float4 bl = *reinterpret_cast<const float4*>(
                    &Bs[buf][kq * 4 + q][j0]);
                const float4 bh = *reinterpret_cast<const float4*>(
                    &Bs[buf][kq * 4 + q][256 + j0]);
#pragma unroll
                for (int i = 0; i < TPW; ++i) {
                    const float av = (q == 0) ? a[i].x : (q == 1) ? a[i].y
                                   : (q == 2) ? a[i].z : a[i].w;
                    float* A8 = acc[i];
                    A8[0] = fmaf(av, bl.x, A8[0]);
                    A8[1] = fmaf(av, bl.y, A8[1]);
                    A8[2] = fmaf(av, bl.z, A8[2]);
                    A8[3] = fmaf(av, bl.w, A8[3]);
                    A8[4] = fmaf(av, bh.x, A8[4]);
                    A8[5] = fmaf(av, bh.y, A8[5]);
                    A8[6] = fmaf(av, bh.z, A8[6]);
                    A8[7] = fmaf(av, bh.w, A8[7]);
                }
            }
        }
        __syncthreads();
        buf ^= 1;
    }

    // --- epilogue: exact GELU + W2 dot, 64-lane butterfly reduce per token ---
    const float4 w2a = *reinterpret_cast<const float4*>(&W2[j0]);
    const float4 w2b = *reinterpret_cast<const float4*>(&W2[256 + j0]);
    const float4 b1a = *reinterpret_cast<const float4*>(&b1g[j0]);
    const float4 b1b = *reinterpret_cast<const float4*>(&b1g[256 + j0]);
    const float ww[8] = {w2a.x, w2a.y, w2a.z, w2a.w, w2b.x, w2b.y, w2b.z, w2b.w};
    const float bb[8] = {b1a.x, b1a.y, b1a.z, b1a.w, b1b.x, b1b.y, b1b.z, b1b.w};

    const float bias2 = b2g[0];
#pragma unroll
    for (int i = 0; i < TPW; ++i) {
        float s = 0.0f;
#pragma unroll
        for (int jj = 0; jj < 8; ++jj) {
            const float h = acc[i][jj] + bb[jj];
            const float g = 0.5f * h * (1.0f + erff(h * 0.70710678118654752f));
            s = fmaf(g, ww[jj], s);
        }
#pragma unroll
        for (int off = 32; off > 0; off >>= 1)
            s += __shfl_xor(s, off, 64);
        if (lane == 0) scores[gtok0 + t0 + i] = s + bias2;
    }
}

// ---------------------------------------------------------------------------
// Block-wide exclusive scan (1024 threads, one int per thread). lds >= 16 ints.
// ---------------------------------------------------------------------------
__device__ __forceinline__ int blk_excl_scan_1024(int v, int tid, int* lds, int* tot)
{
    const int lane = tid & 63;
    const int wid  = tid >> 6;
    int x = v;
#pragma unroll
    for (int d = 1; d < 64; d <<= 1) {
        const int y = __shfl_up(x, d, 64);
        if (lane >= d) x += y;
    }
    if (lane == 63) lds[wid] = x;          // inclusive wave sums
    __syncthreads();
    if (wid == 0) {
        int w = (lane < 16) ? lds[lane] : 0;
#pragma unroll
        for (int d = 1; d < 16; d <<= 1) {
            const int y = __shfl_up(w, d, 64);
            if (lane >= d) w += y;
        }
        if (lane < 16) lds[lane] = w;      // inclusive scanned wave sums
    }
    __syncthreads();
    const int wave_off = (wid == 0) ? 0 : lds[wid - 1];
    const int total    = lds[15];
    __syncthreads();                       // lds reusable after return
    *tot = total;
    return wave_off + x - v;               // exclusive prefix
}

// ---------------------------------------------------------------------------
// Kernel B: exact top-k per batch. Bitonic-sort a copy of scores in LDS to get
// the threshold (4096th largest), tie-break by lowest index (matches
// jax.lax.top_k + sort(indices)), emit sorted compacted indices + 0/1 mask.
// ---------------------------------------------------------------------------
__global__ __launch_bounds__(1024)
void dtr_topk_kernel(const float* __restrict__ scores,
                     int* __restrict__ idx_out,
                     float* __restrict__ mask_out)
{
    __shared__ float sv[NTOK];   // 32 KB
    __shared__ int scan_lds[16];

    const int b   = blockIdx.x;
    const int tid = threadIdx.x;
    const float* s = scores + (size_t)b * NTOK;

    for (int i = tid; i < NTOK; i += 1024) sv[i] = s[i];
    __syncthreads();

    // bitonic sort ascending
    for (int k = 2; k <= NTOK; k <<= 1) {
        for (int j = k >> 1; j > 0; j >>= 1) {
            for (int i = tid; i < NTOK; i += 1024) {
                const int ixj = i ^ j;
                if (ixj > i) {
                    const float av = sv[i];
                    const float bv = sv[ixj];
                    const bool asc = ((i & k) == 0);
                    if ((av > bv) == asc) { sv[i] = bv; sv[ixj] = av; }
                }
            }
            __syncthreads();
        }
    }

    const float T = sv[NTOK - NKEEP];   // 4096th largest (ascending pos 4096)

    const int i0 = tid * 8;
    float sc[8];
#pragma unroll
    for (int q = 0; q < 8; ++q) sc[q] = s[i0 + q];

    int sum_g = 0, sum_e = 0;
#pragma unroll
    for (int q = 0; q < 8; ++q) {
        sum_g += (sc[q] > T) ? 1 : 0;
        sum_e += (sc[q] == T) ? 1 : 0;
    }
    int tot_g, tot_e;
    (void)blk_excl_scan_1024(sum_g, tid, scan_lds, &tot_g);
    const int off_e = blk_excl_scan_1024(sum_e, tid, scan_lds, &tot_e);

    const int need = NKEEP - tot_g;     // how many ==T to keep (lowest index first)

    int keep[8];
    int sum_k = 0;
    int er = off_e;
#pragma unroll
    for (int q = 0; q < 8; ++q) {
        int kf = 0;
        if (sc[q] > T) kf = 1;
        else if (sc[q] == T) { kf = (er < need) ? 1 : 0; ++er; }
        keep[q] = kf;
        sum_k += kf;
    }
    int tot_k;
    int pos = blk_excl_scan_1024(sum_k, tid, scan_lds, &tot_k);

#pragma unroll
    for (int q = 0; q < 8; ++q) {
        mask_out[(size_t)b * NTOK + i0 + q] = keep[q] ? 1.0f : 0.0f;
        if (keep[q]) {
            idx_out[(size_t)b * NKEEP + pos] = i0 + q;
            ++pos;
        }
    }
}

// ---------------------------------------------------------------------------
// Kernel C: gather selected token rows. One block per (b, kpos): 1024 floats.
// ---------------------------------------------------------------------------
__global__ __launch_bounds__(256)
void dtr_gather_kernel(const float* __restrict__ tokens,
                       const int* __restrict__ idx,
                       float* __restrict__ selected)
{
    const int g    = blockIdx.x;        // 0 .. NB*NKEEP-1
    const int b    = g >> 12;           // / NKEEP
    const int src  = idx[g];
    const float4* sp = reinterpret_cast<const float4*>(
        tokens + ((size_t)b * NTOK + (size_t)src) * DIM);
    float4* dp = reinterpret_cast<float4*>(selected + (size_t)g * DIM);
    dp[threadIdx.x] = sp[threadIdx.x];
}

// ---------------------------------------------------------------------------
extern "C" void kernel_launch(void* const* d_in, const int* in_sizes, int n_in,
                              void* d_out, int out_size, void* d_ws, size_t ws_size,
                              hipStream_t stream)
{
    const float* tokens = (const float*)d_in[0];  // [4,8192,1024]
    const float* W1     = (const float*)d_in[1];  // [1024,512]
    const float* b1     = (const float*)d_in[2];  // [512]
    const float* W2     = (const float*)d_in[3];  // [512,1]
    const float* b2     = (const float*)d_in[4];  // [1]

    float* out      = (float*)d_out;
    float* selected = out;                                   // 4*4096*1024
    float* mask     = out + (size_t)NB * NKEEP * DIM;        // 4*8192

    float* scores = (float*)d_ws;                            // 32768 f32
    int*   idx    = (int*)((char*)d_ws + (size_t)NB * NTOK * sizeof(float));

    dtr_scores_kernel<<<(NB * NTOK) / TM, 512, 0, stream>>>(
        tokens, W1, b1, W2, b2, scores);
    dtr_topk_kernel<<<NB, 1024, 0, stream>>>(scores, idx, mask);
    dtr_gather_kernel<<<NB * NKEEP, 256, 0, stream>>>(tokens, idx, selected);
}

// Round 5
// 643.915 us; speedup vs baseline: 2.0821x; 1.1493x over previous
//
#include <hip/hip_runtime.h>
#include <hip/hip_bf16.h>
#include <math.h>

#define NB    4
#define NTOK  8192
#define DIM   1024
#define HDIM  512
#define NKEEP 4096
#define MARG  0.06f   // candidate half-band; bf16 score err rms ~1.6e-3 -> 35 sigma

typedef __attribute__((ext_vector_type(8))) short bf16x8;
typedef __attribute__((ext_vector_type(4))) float f32x4;

__device__ __forceinline__ short f2bf(float x) {       // RNE f32->bf16
    unsigned u = __builtin_bit_cast(unsigned, x);
    unsigned r = (u + 0x7FFFu + ((u >> 16) & 1u)) >> 16;
    return (short)r;
}
__device__ __forceinline__ float gelu_exact(float h) {
    return 0.5f * h * (1.0f + erff(h * 0.70710678118654752f));
}

#define GLD16(g, s) __builtin_amdgcn_global_load_lds(                       \
    (const __attribute__((address_space(1))) void*)(g),                    \
    (__attribute__((address_space(3))) void*)(s), 16, 0, 0)

// ---------------------------------------------------------------------------
// P0: repack W1 (fp32 [K=1024][N=512]) into bf16 MFMA-B fragment order:
// idx = (((kstep*32 + ntile)*64) + lane)*8 + e ; k = kstep*32+(lane>>4)*8+e,
// n = ntile*16 + (lane&15). 1 MB, L2-resident.
// ---------------------------------------------------------------------------
__global__ __launch_bounds__(256)
void dtr_prep_w1(const float* __restrict__ W1, short* __restrict__ w1f)
{
    const int idx = blockIdx.x * 256 + threadIdx.x;    // 524288 total
    const int e = idx & 7, l = (idx >> 3) & 63, t = (idx >> 9) & 31, s = idx >> 14;
    const int k = s * 32 + (l >> 4) * 8 + e;
    const int n = t * 16 + (l & 15);
    w1f[idx] = f2bf(W1[(size_t)k * HDIM + n]);
}

// ---------------------------------------------------------------------------
// A1: approximate scores via bf16 MFMA (16x16x32). 1024 blocks x 256 thr.
// Block: 32 tokens (two 16-row A-tiles). Wave w: ntiles w*8..w*8+7 (128 cols).
// A loaded from global (rows coalesce per 16-lane group), converted to bf16.
// B frags from w1f, fully coalesced 16B/lane. No LDS staging needed.
// ---------------------------------------------------------------------------
__global__ __launch_bounds__(256)
void dtr_a1_approx(const float* __restrict__ tokens,
                   const short* __restrict__ w1f,
                   const float* __restrict__ b1g,
                   const float* __restrict__ W2,
                   const float* __restrict__ b2g,
                   float* __restrict__ sapx)
{
    __shared__ float part[4][32];
    const int tid  = threadIdx.x;
    const int w    = tid >> 6;
    const int lane = tid & 63;
    const int tok0 = blockIdx.x * 32;
    const int arow = lane & 15;
    const int kg   = lane >> 4;

    const float* a0base = tokens + (size_t)(tok0 + arow) * DIM + kg * 8;
    const float* a1base = a0base + (size_t)16 * DIM;

    f32x4 acc[2][8];
#pragma unroll
    for (int at = 0; at < 2; ++at)
#pragma unroll
        for (int t = 0; t < 8; ++t) acc[at][t] = (f32x4){0.f, 0.f, 0.f, 0.f};

    for (int s = 0; s < 32; ++s) {
        bf16x8 af[2];
#pragma unroll
        for (int at = 0; at < 2; ++at) {
            const float* ab = at ? a1base : a0base;
            const float4 f0 = *reinterpret_cast<const float4*>(ab + s * 32);
            const float4 f1 = *reinterpret_cast<const float4*>(ab + s * 32 + 4);
            af[at][0] = f2bf(f0.x); af[at][1] = f2bf(f0.y);
            af[at][2] = f2bf(f0.z); af[at][3] = f2bf(f0.w);
            af[at][4] = f2bf(f1.x); af[at][5] = f2bf(f1.y);
            af[at][6] = f2bf(f1.z); af[at][7] = f2bf(f1.w);
        }
        const short* bb = w1f + ((size_t)(s * 32 + w * 8) * 64 + lane) * 8;
#pragma unroll
        for (int t = 0; t < 8; ++t) {
            const bf16x8 bf = *reinterpret_cast<const bf16x8*>(bb + (size_t)t * 512);
            acc[0][t] = __builtin_amdgcn_mfma_f32_16x16x32_bf16(af[0], bf, acc[0][t], 0, 0, 0);
            acc[1][t] = __builtin_amdgcn_mfma_f32_16x16x32_bf16(af[1], bf, acc[1][t], 0, 0, 0);
        }
    }

    // epilogue: D mapping col=lane&15, row=(lane>>4)*4+reg (m89-verified)
#pragma unroll
    for (int at = 0; at < 2; ++at) {
        float pr[4] = {0.f, 0.f, 0.f, 0.f};
#pragma unroll
        for (int t = 0; t < 8; ++t) {
            const int n = (w * 8 + t) * 16 + (lane & 15);
            const float b1v = b1g[n], w2v = W2[n];
#pragma unroll
            for (int r = 0; r < 4; ++r)
                pr[r] = fmaf(gelu_exact(acc[at][t][r] + b1v), w2v, pr[r]);
        }
#pragma unroll
        for (int r = 0; r < 4; ++r) {
#pragma unroll
            for (int off = 1; off < 16; off <<= 1)
                pr[r] += __shfl_xor(pr[r], off, 64);
        }
        if ((lane & 15) == 0) {
#pragma unroll
            for (int r = 0; r < 4; ++r)
                part[w][at * 16 + (lane >> 4) * 4 + r] = pr[r];
        }
    }
    __syncthreads();
    if (tid < 32) {
        sapx[tok0 + tid] = part[0][tid] + part[1][tid] + part[2][tid]
                         + part[3][tid] + b2g[0];
    }
}

// ---------------------------------------------------------------------------
// Block-wide exclusive scan (1024 threads). lds >= 16 ints.
// ---------------------------------------------------------------------------
__device__ __forceinline__ int blk_excl_scan_1024(int v, int tid, int* lds, int* tot)
{
    const int lane = tid & 63;
    const int wid  = tid >> 6;
    int x = v;
#pragma unroll
    for (int d = 1; d < 64; d <<= 1) {
        const int y = __shfl_up(x, d, 64);
        if (lane >= d) x += y;
    }
    if (lane == 63) lds[wid] = x;
    __syncthreads();
    if (wid == 0) {
        int ww = (lane < 16) ? lds[lane] : 0;
#pragma unroll
        for (int d = 1; d < 16; d <<= 1) {
            const int y = __shfl_up(ww, d, 64);
            if (lane >= d) ww += y;
        }
        if (lane < 16) lds[lane] = ww;
    }
    __syncthreads();
    const int wave_off = (wid == 0) ? 0 : lds[wid - 1];
    const int total    = lds[15];
    __syncthreads();
    *tot = total;
    return wave_off + x - v;
}

// ---------------------------------------------------------------------------
// B1: per batch, bitonic-sort approx scores -> T_apx (4096th largest);
// compact candidate list {i : |s_apx - T| <= MARG}.
// ---------------------------------------------------------------------------
__global__ __launch_bounds__(1024)
void dtr_b1_cand(const float* __restrict__ sapx,
                 float* __restrict__ T_out, int* __restrict__ cnt_out,
                 int* __restrict__ cand)
{
    __shared__ float sv[NTOK];
    __shared__ int scan_lds[16];
    const int b = blockIdx.x, tid = threadIdx.x;
    const float* s = sapx + (size_t)b * NTOK;

    for (int i = tid; i < NTOK; i += 1024) sv[i] = s[i];
    __syncthreads();
    for (int k = 2; k <= NTOK; k <<= 1)
        for (int j = k >> 1; j > 0; j >>= 1) {
            for (int i = tid; i < NTOK; i += 1024) {
                const int ixj = i ^ j;
                if (ixj > i) {
                    const float av = sv[i], bv = sv[ixj];
                    if ((av > bv) == ((i & k) == 0)) { sv[i] = bv; sv[ixj] = av; }
                }
            }
            __syncthreads();
        }
    const float T = sv[NTOK - NKEEP];
    if (tid == 0) T_out[b] = T;

    const int i0 = tid * 8;
    int cf[8], cs = 0;
#pragma unroll
    for (int q = 0; q < 8; ++q) {
        const float x = s[i0 + q];
        cf[q] = (x >= T - MARG) && (x <= T + MARG);
        cs += cf[q];
    }
    int tot;
    int pos = blk_excl_scan_1024(cs, tid, scan_lds, &tot);
#pragma unroll
    for (int q = 0; q < 8; ++q)
        if (cf[q]) cand[(size_t)b * NTOK + pos++] = i0 + q;
    if (tid == 0) cnt_out[b] = tot;
}

// ---------------------------------------------------------------------------
// A2: exact fp32 rescore of candidates. 256 blocks x 512 thr; grid-stride over
// 16-candidate groups. Inner loop = R2's proven conflict-free structure:
// wave w -> 2 tokens (broadcast A from global), lane j={lane*4..+3,256+...},
// W1 LDS-staged (GLD16, double-buffered). Pad slots rescore token 0 (benign,
// identical-value writes).
// ---------------------------------------------------------------------------
__global__ __launch_bounds__(512)
void dtr_a2_rescore(const float* __restrict__ tokens,
                    const float* __restrict__ W1,
                    const float* __restrict__ b1g,
                    const float* __restrict__ W2,
                    const float* __restrict__ b2g,
                    const int* __restrict__ cnt_in,
                    const int* __restrict__ cand,
                    float* __restrict__ sex)
{
    __shared__ __align__(16) float Bs[2][16][HDIM];  // 64 KB
    const int tid  = threadIdx.x;
    const int w    = tid >> 6;
    const int lane = tid & 63;
    const int j0   = lane * 4;

    const float4 w2a = *reinterpret_cast<const float4*>(&W2[j0]);
    const float4 w2b = *reinterpret_cast<const float4*>(&W2[256 + j0]);
    const float4 b1a = *reinterpret_cast<const float4*>(&b1g[j0]);
    const float4 b1b = *reinterpret_cast<const float4*>(&b1g[256 + j0]);
    const float ww[8] = {w2a.x, w2a.y, w2a.z, w2a.w, w2b.x, w2b.y, w2b.z, w2b.w};
    const float bb[8] = {b1a.x, b1a.y, b1a.z, b1a.w, b1b.x, b1b.y, b1b.z, b1b.w};
    const float bias2 = b2g[0];

    for (int g = blockIdx.x; g < 2048; g += 256) {
        const int b    = g >> 9;             // 512 groups of 16 per batch
        const int base = (g & 511) * 16;
        const int cnt  = cnt_in[b];
        if (base >= cnt) continue;           // block-uniform skip

        int tk[2];
#pragma unroll
        for (int u = 0; u < 2; ++u) {
            const int slot = base + w * 2 + u;
            tk[u] = (slot < cnt) ? cand[(size_t)b * NTOK + slot] : 0;
        }
        const float* ar[2] = {
            tokens + ((size_t)b * NTOK + tk[0]) * DIM,
            tokens + ((size_t)b * NTOK + tk[1]) * DIM };

        float acc[2][8];
#pragma unroll
        for (int u = 0; u < 2; ++u)
#pragma unroll
            for (int jj = 0; jj < 8; ++jj) acc[u][jj] = 0.0f;

        auto stageB = [&](int buf, int c) {
            const float* gb = W1 + (size_t)c * 16 * HDIM;
            float* sb = &Bs[buf][0][0];
#pragma unroll
            for (int p = 0; p < 4; ++p) {
                const int f = tid * 4 + p * 2048;
                GLD16(gb + f, sb + f);
            }
        };

        stageB(0, 0);
        __syncthreads();
        int buf = 0;
        for (int c = 0; c < 64; ++c) {
            if (c + 1 < 64) stageB(buf ^ 1, c + 1);
            const int kb = c * 16;
#pragma unroll
            for (int kq = 0; kq < 4; ++kq) {
                float4 av[2];
#pragma unroll
                for (int u = 0; u < 2; ++u)
                    av[u] = *reinterpret_cast<const float4*>(ar[u] + kb + kq * 4);
#pragma unroll
                for (int q = 0; q < 4; ++q) {
                    const float4 bl = *reinterpret_cast<const float4*>(&Bs[buf][kq * 4 + q][j0]);
                    const float4 bh = *reinterpret_cast<const float4*>(&Bs[buf][kq * 4 + q][256 + j0]);
#pragma unroll
                    for (int u = 0; u < 2; ++u) {
                        const float a = (q == 0) ? av[u].x : (q == 1) ? av[u].y
                                      : (q == 2) ? av[u].z : av[u].w;
                        float* A8 = acc[u];
                        A8[0] = fmaf(a, bl.x, A8[0]);
                        A8[1] = fmaf(a, bl.y, A8[1]);
                        A8[2] = fmaf(a, bl.z, A8[2]);
                        A8[3] = fmaf(a, bl.w, A8[3]);
                        A8[4] = fmaf(a, bh.x, A8[4]);
                        A8[5] = fmaf(a, bh.y, A8[5]);
                        A8[6] = fmaf(a, bh.z, A8[6]);
                        A8[7] = fmaf(a, bh.w, A8[7]);
                    }
                }
            }
            __syncthreads();
            buf ^= 1;
        }

#pragma unroll
        for (int u = 0; u < 2; ++u) {
            float s = 0.0f;
#pragma unroll
            for (int jj = 0; jj < 8; ++jj)
                s = fmaf(gelu_exact(acc[u][jj] + bb[jj]), ww[jj], s);
#pragma unroll
            for (int off = 32; off > 0; off >>= 1)
                s += __shfl_xor(s, off, 64);
            if (lane == 0) sex[(size_t)b * NTOK + tk[u]] = s + bias2;
        }
    }
}

// ---------------------------------------------------------------------------
// B2: final selection. def_in = s_apx > T+M (provably in). r = 4096-#def_in.
// Sort candidates desc by (exact score, idx asc) -> choose top r. Scan ->
// sorted indices + mask.
// ---------------------------------------------------------------------------
__global__ __launch_bounds__(1024)
void dtr_b2_select(const float* __restrict__ sapx,
                   const float* __restrict__ sex,
                   const float* __restrict__ T_in,
                   const int* __restrict__ cnt_in,
                   const int* __restrict__ cand,
                   int* __restrict__ idx_out,
                   float* __restrict__ mask_out)
{
    __shared__ float ss[NTOK];
    __shared__ int   si[NTOK];
    __shared__ unsigned char kb[NTOK];
    __shared__ int scan_lds[16];
    const int b = blockIdx.x, tid = threadIdx.x;
    const float T  = T_in[b];
    const int  cnt = cnt_in[b];
    const float* s = sapx + (size_t)b * NTOK;

    const int i0 = tid * 8;
    int df[8], dsum = 0;
#pragma unroll
    for (int q = 0; q < 8; ++q) {
        df[q] = s[i0 + q] > T + MARG;
        dsum += df[q];
    }
    int n_in;
    (void)blk_excl_scan_1024(dsum, tid, scan_lds, &n_in);
    const int r = NKEEP - n_in;

    int P = 1024;
    while (P < cnt) P <<= 1;
    for (int i = tid; i < P; i += 1024) {
        if (i < cnt) {
            const int t = cand[(size_t)b * NTOK + i];
            si[i] = t;
            ss[i] = sex[(size_t)b * NTOK + t];
        } else { si[i] = 0x7fffffff; ss[i] = -3.0e38f; }
    }
    for (int i = tid; i < NTOK; i += 1024) kb[i] = 0;
    __syncthreads();

    // bitonic: ascending by (-score, idx)
    for (int k = 2; k <= P; k <<= 1)
        for (int j = k >> 1; j > 0; j >>= 1) {
            for (int i = tid; i < P; i += 1024) {
                const int ixj = i ^ j;
                if (ixj > i) {
                    const float as = ss[i], bs = ss[ixj];
                    const int   ai = si[i], bi = si[ixj];
                    const bool gt = (as < bs) || (as == bs && ai > bi);
                    if (gt == ((i & k) == 0)) {
                        ss[i] = bs; ss[ixj] = as;
                        si[i] = bi; si[ixj] = ai;
                    }
                }
            }
            __syncthreads();
        }

    for (int i = tid; i < r; i += 1024)
        if (si[i] < NTOK) kb[si[i]] = 1;
    __syncthreads();

    int kf[8], ks = 0;
#pragma unroll
    for (int q = 0; q < 8; ++q) {
        kf[q] = df[q] | (int)kb[i0 + q];
        ks += kf[q];
    }
    int tot;
    int pos = blk_excl_scan_1024(ks, tid, scan_lds, &tot);
#pragma unroll
    for (int q = 0; q < 8; ++q) {
        mask_out[(size_t)b * NTOK + i0 + q] = kf[q] ? 1.0f : 0.0f;
        if (kf[q]) idx_out[(size_t)b * NKEEP + pos++] = i0 + q;
    }
}

// ---------------------------------------------------------------------------
// Gather selected rows.
// ---------------------------------------------------------------------------
__global__ __launch_bounds__(256)
void dtr_gather_kernel(const float* __restrict__ tokens,
                       const int* __restrict__ idx,
                       float* __restrict__ selected)
{
    const int g   = blockIdx.x;
    const int b   = g >> 12;
    const int src = idx[g];
    const float4* sp = reinterpret_cast<const float4*>(
        tokens + ((size_t)b * NTOK + (size_t)src) * DIM);
    float4* dp = reinterpret_cast<float4*>(selected + (size_t)g * DIM);
    dp[threadIdx.x] = sp[threadIdx.x];
}

// ---------------------------------------------------------------------------
extern "C" void kernel_launch(void* const* d_in, const int* in_sizes, int n_in,
                              void* d_out, int out_size, void* d_ws, size_t ws_size,
                              hipStream_t stream)
{
    const float* tokens = (const float*)d_in[0];
    const float* W1     = (const float*)d_in[1];
    const float* b1     = (const float*)d_in[2];
    const float* W2     = (const float*)d_in[3];
    const float* b2     = (const float*)d_in[4];

    float* out      = (float*)d_out;
    float* selected = out;
    float* mask     = out + (size_t)NB * NKEEP * DIM;

    char* w = (char*)d_ws;
    float* sapx = (float*)(w);                 // 4*8192 f32
    float* sex  = (float*)(w + 131072);        // 4*8192 f32
    float* Tpx  = (float*)(w + 262144);        // 4 f32
    int*   ccnt = (int*)  (w + 262160);        // 4 i32
    int*   cand = (int*)  (w + 262400);        // 4*8192 i32
    short* w1f  = (short*)(w + 393472);        // 512*1024 bf16 (1 MB)
    int*   idx  = (int*)  (w + 1441792);       // 4*4096 i32

    dtr_prep_w1<<<2048, 256, 0, stream>>>(W1, w1f);
    dtr_a1_approx<<<(NB * NTOK) / 32, 256, 0, stream>>>(tokens, w1f, b1, W2, b2, sapx);
    dtr_b1_cand<<<NB, 1024, 0, stream>>>(sapx, Tpx, ccnt, cand);
    dtr_a2_rescore<<<256, 512, 0, stream>>>(tokens, W1, b1, W2, b2, ccnt, cand, sex);
    dtr_b2_select<<<NB, 1024, 0, stream>>>(sapx, sex, Tpx, ccnt, cand, idx, mask);
    dtr_gather_kernel<<<NB * NKEEP, 256, 0, stream>>>(tokens, idx, selected);
}

// Round 6
// 261.360 us; speedup vs baseline: 5.1296x; 2.4637x over previous
//
#include <hip/hip_runtime.h>
#include <hip/hip_bf16.h>
#include <math.h>

#define NB    4
#define NTOK  8192
#define DIM   1024
#define HDIM  512
#define NKEEP 4096
#define MARG  0.06f     // candidate half-band; bf16 score err rms ~1.6e-3
#define A2_MAXC 1024    // candidate capacity per batch (expected ~330)

typedef __attribute__((ext_vector_type(8))) short bf16x8;
typedef __attribute__((ext_vector_type(4))) float f32x4;

__device__ __forceinline__ short f2bf(float x) {       // RNE f32->bf16
    unsigned u = __builtin_bit_cast(unsigned, x);
    unsigned r = (u + 0x7FFFu + ((u >> 16) & 1u)) >> 16;
    return (short)r;
}
__device__ __forceinline__ float gelu_exact(float h) {
    return 0.5f * h * (1.0f + erff(h * 0.70710678118654752f));
}

// ---------------------------------------------------------------------------
// P0: repack W1 (fp32 [K=1024][N=512]) into bf16 MFMA-B fragment order.
// ---------------------------------------------------------------------------
__global__ __launch_bounds__(256)
void dtr_prep_w1(const float* __restrict__ W1, short* __restrict__ w1f)
{
    const int idx = blockIdx.x * 256 + threadIdx.x;    // 524288 total
    const int e = idx & 7, l = (idx >> 3) & 63, t = (idx >> 9) & 31, s = idx >> 14;
    const int k = s * 32 + (l >> 4) * 8 + e;
    const int n = t * 16 + (l & 15);
    w1f[idx] = f2bf(W1[(size_t)k * HDIM + n]);
}

// ---------------------------------------------------------------------------
// A1: approximate scores via bf16 MFMA (16x16x32). 1024 blocks x 256 thr.
// Block: 32 tokens (two 16-row A-tiles). Wave w: ntiles w*8..w*8+7.
// ---------------------------------------------------------------------------
__global__ __launch_bounds__(256)
void dtr_a1_approx(const float* __restrict__ tokens,
                   const short* __restrict__ w1f,
                   const float* __restrict__ b1g,
                   const float* __restrict__ W2,
                   const float* __restrict__ b2g,
                   float* __restrict__ sapx)
{
    __shared__ float part[4][32];
    const int tid  = threadIdx.x;
    const int w    = tid >> 6;
    const int lane = tid & 63;
    const int tok0 = blockIdx.x * 32;
    const int arow = lane & 15;
    const int kg   = lane >> 4;

    const float* a0base = tokens + (size_t)(tok0 + arow) * DIM + kg * 8;
    const float* a1base = a0base + (size_t)16 * DIM;

    f32x4 acc[2][8];
#pragma unroll
    for (int at = 0; at < 2; ++at)
#pragma unroll
        for (int t = 0; t < 8; ++t) acc[at][t] = (f32x4){0.f, 0.f, 0.f, 0.f};

    for (int s = 0; s < 32; ++s) {
        bf16x8 af[2];
#pragma unroll
        for (int at = 0; at < 2; ++at) {
            const float* ab = at ? a1base : a0base;
            const float4 f0 = *reinterpret_cast<const float4*>(ab + s * 32);
            const float4 f1 = *reinterpret_cast<const float4*>(ab + s * 32 + 4);
            af[at][0] = f2bf(f0.x); af[at][1] = f2bf(f0.y);
            af[at][2] = f2bf(f0.z); af[at][3] = f2bf(f0.w);
            af[at][4] = f2bf(f1.x); af[at][5] = f2bf(f1.y);
            af[at][6] = f2bf(f1.z); af[at][7] = f2bf(f1.w);
        }
        const short* bb = w1f + ((size_t)(s * 32 + w * 8) * 64 + lane) * 8;
#pragma unroll
        for (int t = 0; t < 8; ++t) {
            const bf16x8 bf = *reinterpret_cast<const bf16x8*>(bb + (size_t)t * 512);
            acc[0][t] = __builtin_amdgcn_mfma_f32_16x16x32_bf16(af[0], bf, acc[0][t], 0, 0, 0);
            acc[1][t] = __builtin_amdgcn_mfma_f32_16x16x32_bf16(af[1], bf, acc[1][t], 0, 0, 0);
        }
    }

    // D mapping col=lane&15, row=(lane>>4)*4+reg (m89-verified)
#pragma unroll
    for (int at = 0; at < 2; ++at) {
        float pr[4] = {0.f, 0.f, 0.f, 0.f};
#pragma unroll
        for (int t = 0; t < 8; ++t) {
            const int n = (w * 8 + t) * 16 + (lane & 15);
            const float b1v = b1g[n], w2v = W2[n];
#pragma unroll
            for (int r = 0; r < 4; ++r)
                pr[r] = fmaf(gelu_exact(acc[at][t][r] + b1v), w2v, pr[r]);
        }
#pragma unroll
        for (int r = 0; r < 4; ++r) {
#pragma unroll
            for (int off = 1; off < 16; off <<= 1)
                pr[r] += __shfl_xor(pr[r], off, 64);
        }
        if ((lane & 15) == 0) {
#pragma unroll
            for (int r = 0; r < 4; ++r)
                part[w][at * 16 + (lane >> 4) * 4 + r] = pr[r];
        }
    }
    __syncthreads();
    if (tid < 32) {
        sapx[tok0 + tid] = part[0][tid] + part[1][tid] + part[2][tid]
                         + part[3][tid] + b2g[0];
    }
}

// ---------------------------------------------------------------------------
// Block-wide exclusive scan (1024 threads). lds >= 16 ints.
// ---------------------------------------------------------------------------
__device__ __forceinline__ int blk_excl_scan_1024(int v, int tid, int* lds, int* tot)
{
    const int lane = tid & 63;
    const int wid  = tid >> 6;
    int x = v;
#pragma unroll
    for (int d = 1; d < 64; d <<= 1) {
        const int y = __shfl_up(x, d, 64);
        if (lane >= d) x += y;
    }
    if (lane == 63) lds[wid] = x;
    __syncthreads();
    if (wid == 0) {
        int ww = (lane < 16) ? lds[lane] : 0;
#pragma unroll
        for (int d = 1; d < 16; d <<= 1) {
            const int y = __shfl_up(ww, d, 64);
            if (lane >= d) ww += y;
        }
        if (lane < 16) lds[lane] = ww;
    }
    __syncthreads();
    const int wave_off = (wid == 0) ? 0 : lds[wid - 1];
    const int total    = lds[15];
    __syncthreads();
    *tot = total;
    return wave_off + x - v;
}

// ---------------------------------------------------------------------------
// B1: radix-select the exact 4096th-largest approx score (4 x 8-bit passes on
// sign-flipped uint keys; LDS histogram + reversed block scan). Then compact
// the candidate band {i : |s_apx - T| <= MARG}. No bitonic sort.
// ---------------------------------------------------------------------------
__global__ __launch_bounds__(1024)
void dtr_b1_cand(const float* __restrict__ sapx,
                 float* __restrict__ T_out, int* __restrict__ cnt_out,
                 int* __restrict__ cand)
{
    __shared__ int hist[256];
    __shared__ int scan_lds[16];
    __shared__ unsigned sh_pref;
    __shared__ int sh_rank;
    const int b = blockIdx.x, tid = threadIdx.x;
    const float* s = sapx + (size_t)b * NTOK;

    const int i0 = tid * 8;
    unsigned keys[8];
    float sc[8];
#pragma unroll
    for (int q = 0; q < 8; ++q) {
        sc[q] = s[i0 + q];
        const unsigned u = __builtin_bit_cast(unsigned, sc[q]);
        keys[q] = u ^ ((u >> 31) ? 0xFFFFFFFFu : 0x80000000u);  // order-preserving
    }
    if (tid == 0) { sh_pref = 0u; sh_rank = NKEEP; }

    for (int level = 3; level >= 0; --level) {
        const int sh = level * 8;
        if (tid < 256) hist[tid] = 0;
        __syncthreads();                       // also publishes sh_pref/sh_rank
        const unsigned pref = sh_pref;
        const int rank = sh_rank;
#pragma unroll
        for (int q = 0; q < 8; ++q) {
            const unsigned u = keys[q];
            const bool match = (level == 3) || (((u ^ pref) >> (sh + 8)) == 0u);
            if (match) atomicAdd(&hist[(u >> sh) & 255], 1);
        }
        __syncthreads();
        const int v = (tid < 256) ? hist[255 - tid] : 0;  // reversed -> suffix
        int tot;
        const int pos = blk_excl_scan_1024(v, tid, scan_lds, &tot);
        if (tid < 256 && pos < rank && rank <= pos + v) {  // unique thread
            sh_pref = pref | ((unsigned)(255 - tid) << sh);
            sh_rank = rank - pos;
        }
        __syncthreads();
    }
    const unsigned ku = sh_pref;               // exact key of 4096th largest
    const unsigned tu = (ku & 0x80000000u) ? (ku ^ 0x80000000u) : ~ku;
    const float T = __builtin_bit_cast(float, tu);
    if (tid == 0) T_out[b] = T;

    int cf[8], cs = 0;
#pragma unroll
    for (int q = 0; q < 8; ++q) {
        cf[q] = (sc[q] >= T - MARG) && (sc[q] <= T + MARG);
        cs += cf[q];
    }
    int tot;
    int pos = blk_excl_scan_1024(cs, tid, scan_lds, &tot);
#pragma unroll
    for (int q = 0; q < 8; ++q)
        if (cf[q]) cand[(size_t)b * NTOK + pos++] = i0 + q;
    if (tid == 0) cnt_out[b] = (tot < A2_MAXC) ? tot : A2_MAXC;
}

// ---------------------------------------------------------------------------
// A2: exact fp32 rescore. One block = 8 candidates, 256 threads. Token rows
// staged in LDS ONCE (32 KB, single barrier); K-loop has NO barriers: thread
// owns h-cols {2t, 2t+1}, streams W1 row-coalesced (float2/k) from L2, token
// values via broadcast ds_read_b128. Deterministic reduction.
// ---------------------------------------------------------------------------
__global__ __launch_bounds__(256)
void dtr_a2_rescore(const float* __restrict__ tokens,
                    const float* __restrict__ W1,
                    const float* __restrict__ b1g,
                    const float* __restrict__ W2,
                    const float* __restrict__ b2g,
                    const int* __restrict__ cnt_in,
                    const int* __restrict__ cand,
                    float* __restrict__ sex)
{
    __shared__ __align__(16) float tk[8][DIM];   // 32 KB
    __shared__ float red[8][4];
    const int tid = threadIdx.x;
    const int b   = blockIdx.x >> 7;             // 128 groups per batch
    const int grp = blockIdx.x & 127;
    const int cnt = cnt_in[b];
    const int base = grp * 8;
    if (base >= cnt) return;

    int ctk[8];
#pragma unroll
    for (int c = 0; c < 8; ++c) {
        const int slot = base + c;
        ctk[c] = cand[(size_t)b * NTOK + (slot < cnt ? slot : base)];
    }
#pragma unroll
    for (int c = 0; c < 8; ++c) {
        const float4 v = *reinterpret_cast<const float4*>(
            tokens + ((size_t)b * NTOK + ctk[c]) * DIM + tid * 4);
        *reinterpret_cast<float4*>(&tk[c][tid * 4]) = v;
    }
    __syncthreads();

    const int j = tid * 2;                       // cols j, j+1
    float acc0[8], acc1[8];
#pragma unroll
    for (int c = 0; c < 8; ++c) { acc0[c] = 0.f; acc1[c] = 0.f; }

    for (int k0 = 0; k0 < DIM; k0 += 4) {
        float4 a[8];
#pragma unroll
        for (int c = 0; c < 8; ++c)
            a[c] = *reinterpret_cast<const float4*>(&tk[c][k0]);  // broadcast
#pragma unroll
        for (int kk = 0; kk < 4; ++kk) {
            const float2 w = *reinterpret_cast<const float2*>(
                &W1[(size_t)(k0 + kk) * HDIM + j]);               // coalesced
#pragma unroll
            for (int c = 0; c < 8; ++c) {
                const float av = (kk == 0) ? a[c].x : (kk == 1) ? a[c].y
                               : (kk == 2) ? a[c].z : a[c].w;
                acc0[c] = fmaf(av, w.x, acc0[c]);
                acc1[c] = fmaf(av, w.y, acc1[c]);
            }
        }
    }

    const float b1v0 = b1g[j], b1v1 = b1g[j + 1];
    const float w20  = W2[j],  w21  = W2[j + 1];
    const int lane = tid & 63, w4 = tid >> 6;
#pragma unroll
    for (int c = 0; c < 8; ++c) {
        float p = fmaf(gelu_exact(acc0[c] + b1v0), w20,
                       gelu_exact(acc1[c] + b1v1) * w21);
#pragma unroll
        for (int off = 32; off > 0; off >>= 1)
            p += __shfl_xor(p, off, 64);
        if (lane == 0) red[c][w4] = p;
    }
    __syncthreads();
    if (tid < 8) {
        const int slot = base + tid;
        if (slot < cnt) {
            const float sv = red[tid][0] + red[tid][1] + red[tid][2]
                           + red[tid][3] + b2g[0];
            sex[(size_t)b * NTOK + cand[(size_t)b * NTOK + slot]] = sv;
        }
    }
}

// ---------------------------------------------------------------------------
// B2: final selection. def_in = s_apx > T+M. r = 4096-#def_in. Bitonic-sort
// candidates by (exact score desc, idx asc), keep top r; scan -> indices+mask.
// ---------------------------------------------------------------------------
__global__ __launch_bounds__(1024)
void dtr_b2_select(const float* __restrict__ sapx,
                   const float* __restrict__ sex,
                   const float* __restrict__ T_in,
                   const int* __restrict__ cnt_in,
                   const int* __restrict__ cand,
                   int* __restrict__ idx_out,
                   float* __restrict__ mask_out)
{
    __shared__ float ss[NTOK];
    __shared__ int   si[NTOK];
    __shared__ unsigned char kb[NTOK];
    __shared__ int scan_lds[16];
    const int b = blockIdx.x, tid = threadIdx.x;
    const float T  = T_in[b];
    const int  cnt = cnt_in[b];
    const float* s = sapx + (size_t)b * NTOK;

    const int i0 = tid * 8;
    int df[8], dsum = 0;
#pragma unroll
    for (int q = 0; q < 8; ++q) {
        df[q] = s[i0 + q] > T + MARG;
        dsum += df[q];
    }
    int n_in;
    (void)blk_excl_scan_1024(dsum, tid, scan_lds, &n_in);
    const int r = NKEEP - n_in;

    int P = 1024;
    while (P < cnt) P <<= 1;
    for (int i = tid; i < P; i += 1024) {
        if (i < cnt) {
            const int t = cand[(size_t)b * NTOK + i];
            si[i] = t;
            ss[i] = sex[(size_t)b * NTOK + t];
        } else { si[i] = 0x7fffffff; ss[i] = -3.0e38f; }
    }
    for (int i = tid; i < NTOK; i += 1024) kb[i] = 0;
    __syncthreads();

    for (int k = 2; k <= P; k <<= 1)
        for (int j = k >> 1; j > 0; j >>= 1) {
            for (int i = tid; i < P; i += 1024) {
                const int ixj = i ^ j;
                if (ixj > i) {
                    const float as = ss[i], bs = ss[ixj];
                    const int   ai = si[i], bi = si[ixj];
                    const bool gt = (as < bs) || (as == bs && ai > bi);
                    if (gt == ((i & k) == 0)) {
                        ss[i] = bs; ss[ixj] = as;
                        si[i] = bi; si[ixj] = ai;
                    }
                }
            }
            __syncthreads();
        }

    for (int i = tid; i < r; i += 1024)
        if (si[i] < NTOK) kb[si[i]] = 1;
    __syncthreads();

    int kf[8], ks = 0;
#pragma unroll
    for (int q = 0; q < 8; ++q) {
        kf[q] = df[q] | (int)kb[i0 + q];
        ks += kf[q];
    }
    int tot;
    int pos = blk_excl_scan_1024(ks, tid, scan_lds, &tot);
#pragma unroll
    for (int q = 0; q < 8; ++q) {
        mask_out[(size_t)b * NTOK + i0 + q] = kf[q] ? 1.0f : 0.0f;
        if (kf[q]) idx_out[(size_t)b * NKEEP + pos++] = i0 + q;
    }
}

// ---------------------------------------------------------------------------
// Gather selected rows.
// ---------------------------------------------------------------------------
__global__ __launch_bounds__(256)
void dtr_gather_kernel(const float* __restrict__ tokens,
                       const int* __restrict__ idx,
                       float* __restrict__ selected)
{
    const int g   = blockIdx.x;
    const int b   = g >> 12;
    const int src = idx[g];
    const float4* sp = reinterpret_cast<const float4*>(
        tokens + ((size_t)b * NTOK + (size_t)src) * DIM);
    float4* dp = reinterpret_cast<float4*>(selected + (size_t)g * DIM);
    dp[threadIdx.x] = sp[threadIdx.x];
}

// ---------------------------------------------------------------------------
extern "C" void kernel_launch(void* const* d_in, const int* in_sizes, int n_in,
                              void* d_out, int out_size, void* d_ws, size_t ws_size,
                              hipStream_t stream)
{
    const float* tokens = (const float*)d_in[0];
    const float* W1     = (const float*)d_in[1];
    const float* b1     = (const float*)d_in[2];
    const float* W2     = (const float*)d_in[3];
    const float* b2     = (const float*)d_in[4];

    float* out      = (float*)d_out;
    float* selected = out;
    float* mask     = out + (size_t)NB * NKEEP * DIM;

    char* w = (char*)d_ws;
    float* sapx = (float*)(w);                 // 4*8192 f32
    float* sex  = (float*)(w + 131072);        // 4*8192 f32
    float* Tpx  = (float*)(w + 262144);        // 4 f32
    int*   ccnt = (int*)  (w + 262160);        // 4 i32
    int*   cand = (int*)  (w + 262400);        // 4*8192 i32
    short* w1f  = (short*)(w + 393472);        // 512*1024 bf16 (1 MB)
    int*   idx  = (int*)  (w + 1441792);       // 4*4096 i32

    dtr_prep_w1<<<2048, 256, 0, stream>>>(W1, w1f);
    dtr_a1_approx<<<(NB * NTOK) / 32, 256, 0, stream>>>(tokens, w1f, b1, W2, b2, sapx);
    dtr_b1_cand<<<NB, 1024, 0, stream>>>(sapx, Tpx, ccnt, cand);
    dtr_a2_rescore<<<NB * 128, 256, 0, stream>>>(tokens, W1, b1, W2, b2, ccnt, cand, sex);
    dtr_b2_select<<<NB, 1024, 0, stream>>>(sapx, sex, Tpx, ccnt, cand, idx, mask);
    dtr_gather_kernel<<<NB * NKEEP, 256, 0, stream>>>(tokens, idx, selected);
}